// Round 7
// baseline (178.888 us; speedup 1.0000x reference)
//
#include <hip/hip_runtime.h>
#include <cstdint>
#include <cstddef>

// ---------------------------------------------------------------------------
// LSTM cell, B=8192, D=H=512, fp32 in/out.
// pre = [x|h] @ Wstack^T + bias ; gates -> c_t, h_t fused in GEMM epilogue.
// Round 7: producer/consumer wave specialization — NO barrier in the K-loop.
// 768 thr = 12 waves, 1 block/CU: waves 0..7 consume (256x128 tile, 4wm x 2wn
// of 64x64), waves 8..11 produce (global_load_lds into a 3-slot ring,
// s_waitcnt vmcnt(0) in the PRODUCER only, publish via LDS atomics).
// Consumers never execute a vmem wait; producer drains overlap MFMA.
// R1-R6 showed the 2-barrier K-loop plateaus at 51-62us regardless of
// occupancy/buffering (2.4x above all serial floors) — this removes it.
// ---------------------------------------------------------------------------

typedef __attribute__((ext_vector_type(8))) short short8;   // 8 bf16 = 4 VGPRs
typedef __attribute__((ext_vector_type(4))) float floatx4;  // MFMA acc

#define AS1(p) ((const __attribute__((address_space(1))) void*)(p))
#define AS3(p) ((__attribute__((address_space(3))) void*)(p))

__device__ __forceinline__ unsigned short f2bf(float f) {
  union { float f; unsigned u; } v; v.f = f;
  unsigned u = v.u;
  return (unsigned short)((u + 0x7fffu + ((u >> 16) & 1u)) >> 16);  // RNE
}

// --------------------------- pack everything -------------------------------
struct PackArgs {
  const float* x; const float* h;
  const float* wx[4]; const float* wh[4];
  const float* bx[4]; const float* bh[4];
  unsigned short* A; unsigned short* B; float* bias;
};

__global__ __launch_bounds__(256) void pack_all_kernel(PackArgs P) {
  const int bid = blockIdx.x;
  if (bid < 8192) {
    int e = (bid * 256 + threadIdx.x) * 4;
    int b = e >> 10, k = e & 1023;
    const float* src = (k < 512) ? (P.x + b * 512 + k)
                                 : (P.h + b * 512 + (k - 512));
    float4 v = *(const float4*)src;
    ushort4 o;
    o.x = f2bf(v.x); o.y = f2bf(v.y); o.z = f2bf(v.z); o.w = f2bf(v.w);
    *(ushort4*)(P.A + e) = o;
  } else {
    int e = ((bid - 8192) * 256 + threadIdx.x) * 4;
    int n = e >> 10, k = e & 1023;
    int g = n >> 9, hh = n & 511;
    const float* src = (k < 512) ? (P.wx[g] + hh * 512 + k)
                                 : (P.wh[g] + hh * 512 + (k - 512));
    float4 v = *(const float4*)src;
    ushort4 o;
    o.x = f2bf(v.x); o.y = f2bf(v.y); o.z = f2bf(v.z); o.w = f2bf(v.w);
    *(ushort4*)(P.B + e) = o;
    if (k == 0) P.bias[n] = P.bx[g][hh] + P.bh[g][hh];
  }
}

// --------------------------- fused GEMM + LSTM epilogue --------------------
// Grid (32,16): tile = 256 batch x (4 gates x 32 hidden). K=1024, BK=64.
// Slot layout (s=0..2 at s*49152): A [0,32768) = [256 rows][128 B],
//                                  B [32768,49152) = [128 rows][128 B].
// Within-row 16B chunks XOR-swizzled by row&7 (conflict-free ds_read_b128).
__global__ __launch_bounds__(768)
void lstm_gemm_kernel(const unsigned short* __restrict__ A,   // [8192][1024]
                      const unsigned short* __restrict__ B,   // [2048][1024]
                      const float* __restrict__ bias,         // [2048]
                      const float* __restrict__ c_prev,       // [8192][512]
                      float* __restrict__ h_out,              // [8192][512]
                      float* __restrict__ c_out) {            // [8192][512]
  __shared__ __align__(16) char smem[147456];   // 3 x 48KB slots
  __shared__ float biasS[128];
  __shared__ int prod_cnt[3];
  __shared__ int cons_cnt[3];

  const int tid  = threadIdx.x;
  const int lane = tid & 63;
  const int w    = tid >> 6;        // wave 0..11
  const int m0   = blockIdx.x * 256;
  const int h0   = blockIdx.y * 32;

  if (tid < 3) { prod_cnt[tid] = 0; cons_cnt[tid] = 0; }
  if (tid < 128) biasS[tid] = bias[(tid >> 5) * 512 + h0 + (tid & 31)];
  __syncthreads();

  const int quad = lane >> 4;
  const int colA = lane & 15;
  const int wm = (w >> 1) * 64;     // consumer M offset (0,64,128,192)
  const int wn = (w & 1) * 64;      // consumer N' offset (0 or 64)

  floatx4 acc[4][4];
#pragma unroll
  for (int i = 0; i < 4; ++i)
#pragma unroll
    for (int j = 0; j < 4; ++j) acc[i][j] = (floatx4){0.f, 0.f, 0.f, 0.f};

  if (w >= 8) {
    // ============================ PRODUCER ================================
    const int p  = w - 8;           // 0..3
    const char* Ag = (const char*)A;
    const char* Bg = (const char*)B;
    const int lrow = lane >> 3;     // 0..7
    const int cl   = lane & 7;
    const int cg   = cl ^ lrow;     // global-chunk swizzle (rows within a
                                    // wave-inst are 8-aligned, r&7 == lrow)
    for (int kt = 0; kt < 16; ++kt) {
      const int s = kt % 3;
      const int g = kt / 3;
      if (g > 0) {                  // wait: all 8 consumers done with prev gen
        while (__atomic_load_n(&cons_cnt[s], __ATOMIC_ACQUIRE) < 8 * g)
          __builtin_amdgcn_s_sleep(1);
      }
      const int kb = kt * 128;
      char* sb = smem + s * 49152;
#pragma unroll
      for (int i = 0; i < 12; ++i) {
        const int t = p + 4 * i;    // 0..47: 32 A-groups then 16 B-groups
        if (t < 32) {
          int r = t * 8 + lrow;     // A tile row 0..255
          __builtin_amdgcn_global_load_lds(
              AS1(Ag + (size_t)(m0 + r) * 2048 + kb + cg * 16),
              AS3(sb + r * 128 + cl * 16), 16, 0, 0);
        } else {
          int r = (t - 32) * 8 + lrow;              // B tile row 0..127
          int grow = (r >> 5) * 512 + h0 + (r & 31);
          __builtin_amdgcn_global_load_lds(
              AS1(Bg + (size_t)grow * 2048 + kb + cg * 16),
              AS3(sb + 32768 + r * 128 + cl * 16), 16, 0, 0);
        }
      }
      __builtin_amdgcn_s_waitcnt(0x0F70);  // vmcnt(0), expcnt/lgkm untouched
      if (lane == 0)
        __atomic_fetch_add(&prod_cnt[s], 1, __ATOMIC_RELEASE);
    }
  } else {
    // ============================ CONSUMER ================================
    for (int kt = 0; kt < 16; ++kt) {
      const int s = kt % 3;
      const int g = kt / 3;
      while (__atomic_load_n(&prod_cnt[s], __ATOMIC_ACQUIRE) < 4 * (g + 1))
        __builtin_amdgcn_s_sleep(1);
      const char* Ab = smem + s * 49152;
      const char* Bb = Ab + 32768;
#pragma unroll
      for (int kk = 0; kk < 2; ++kk) {
        const int off = ((kk * 4 + quad) ^ (colA & 7)) * 16;
        short8 af[4], bfr[4];
#pragma unroll
        for (int mi = 0; mi < 4; ++mi)
          af[mi] = *(const short8*)(Ab + (wm + mi * 16 + colA) * 128 + off);
#pragma unroll
        for (int ni = 0; ni < 4; ++ni)
          bfr[ni] = *(const short8*)(Bb + (wn + ni * 16 + colA) * 128 + off);
#pragma unroll
        for (int mi = 0; mi < 4; ++mi)
#pragma unroll
          for (int ni = 0; ni < 4; ++ni)
            acc[mi][ni] = __builtin_amdgcn_mfma_f32_16x16x32_bf16(
                af[mi], bfr[ni], acc[mi][ni], 0, 0, 0);
      }
      // DS ops retire in order per wave: this add can't pass the ds_reads.
      if (lane == 0)
        __atomic_fetch_add(&cons_cnt[s], 1, __ATOMIC_RELEASE);
    }
  }

  // ------------------- fused epilogue (4 rounds of 64 M-rows) --------------
  __syncthreads();                  // all 12 waves; producers are done
  float* ep = (float*)smem;         // [64][132] padded, overlays slot 0
#pragma unroll
  for (int rd = 0; rd < 4; ++rd) {
    if (w < 8 && (w >> 1) == rd) {  // the 2 consumer waves with wm == rd*64
      // C/D layout: row = quad*4 + rr, col = lane&15
#pragma unroll
      for (int mi = 0; mi < 4; ++mi)
#pragma unroll
        for (int ni = 0; ni < 4; ++ni) {
          int rr0 = mi * 16 + quad * 4;                 // 0..63
          int cc  = wn + ni * 16 + colA;                // 0..127
#pragma unroll
          for (int rr = 0; rr < 4; ++rr)
            ep[(rr0 + rr) * 132 + cc] = acc[mi][ni][rr];
        }
    }
    __syncthreads();
#pragma unroll
    for (int j = 0; j < 3; ++j) {
      int idx = j * 768 + tid;      // 0..2047 (+ guard)
      if (idx < 2048) {
        int mloc = idx >> 5;
        int hh   = idx & 31;
        float pf = ep[mloc * 132 +      hh] + biasS[hh];
        float pi = ep[mloc * 132 + 32 + hh] + biasS[32 + hh];
        float pg = ep[mloc * 132 + 64 + hh] + biasS[64 + hh];
        float po = ep[mloc * 132 + 96 + hh] + biasS[96 + hh];
        float fg = 1.f / (1.f + __expf(-pf));
        float ig = 1.f / (1.f + __expf(-pi));
        float gg = 1.f - 2.f / (1.f + __expf(2.f * pg));
        float og = 1.f / (1.f + __expf(-po));
        int m  = m0 + rd * 64 + mloc;
        int hg = h0 + hh;
        float cp = c_prev[m * 512 + hg];
        float cv = fg * cp + ig * gg;
        float th = 1.f - 2.f / (1.f + __expf(2.f * cv));
        h_out[m * 512 + hg] = og * th;
        c_out[m * 512 + hg] = cv;
      }
    }
    __syncthreads();
  }
}

// ---------------------------------------------------------------------------
extern "C" void kernel_launch(void* const* d_in, const int* in_sizes, int n_in,
                              void* d_out, int out_size, void* d_ws, size_t ws_size,
                              hipStream_t stream) {
  // workspace: A_bf16 (16 MiB) | B_bf16 (4 MiB) | bias (8 KiB)
  char* ws = (char*)d_ws;
  unsigned short* Abf = (unsigned short*)ws;
  unsigned short* Bbf = (unsigned short*)(ws + (size_t)16777216);
  float* bias = (float*)(ws + (size_t)16777216 + 4194304);

  float* hout = (float*)d_out;
  float* cout = hout + (size_t)8192 * 512;

  PackArgs P;
  P.x = (const float*)d_in[0];
  P.h = (const float*)d_in[1];
  // gate order in stacked B: 0=f, 1=i, 2=g(cell), 3=o
  P.wx[0] = (const float*)d_in[3];  P.bx[0] = (const float*)d_in[4];
  P.wh[0] = (const float*)d_in[5];  P.bh[0] = (const float*)d_in[6];
  P.wx[1] = (const float*)d_in[7];  P.bx[1] = (const float*)d_in[8];
  P.wh[1] = (const float*)d_in[9];  P.bh[1] = (const float*)d_in[10];
  P.wx[2] = (const float*)d_in[11]; P.bx[2] = (const float*)d_in[12];
  P.wh[2] = (const float*)d_in[13]; P.bh[2] = (const float*)d_in[14];
  P.wx[3] = (const float*)d_in[15]; P.bx[3] = (const float*)d_in[16];
  P.wh[3] = (const float*)d_in[17]; P.bh[3] = (const float*)d_in[18];
  P.A = Abf; P.B = Bbf; P.bias = bias;

  pack_all_kernel<<<10240, 256, 0, stream>>>(P);

  const float* c = (const float*)d_in[2];
  dim3 grid(32, 16);
  lstm_gemm_kernel<<<grid, 768, 0, stream>>>(Abf, Bbf, bias, c, hout, cout);
}